// Round 5
// baseline (368.898 us; speedup 1.0000x reference)
//
#include <hip/hip_runtime.h>
#include <cstdint>
#include <cstddef>

#define NPTS 8192
#define DDIM 128
#define BATCH 2
#define NROWS (BATCH * NPTS)
#define EPSGAP 4.0f   // hard bound: 2*max|bf16 dot err| <= 3.2 (Cauchy-Schwarz), +margin
#define NCOLT 64      // 8192 / 128 column tiles (partials per row)
#define RCAP 2048     // candidate-list capacity in recheck

typedef __attribute__((ext_vector_type(8))) short short8v;
typedef __attribute__((ext_vector_type(4))) float f32x4;

typedef __attribute__((address_space(3))) unsigned int as3_uint;
typedef const __attribute__((address_space(1))) unsigned int as1_uint;

static __device__ __forceinline__ unsigned short f2bf_rne(float x) {
    unsigned int u = __float_as_uint(x);
    unsigned int r = (u + 0x7FFFu + ((u >> 16) & 1u)) >> 16;
    return (unsigned short)r;
}

// ---- split fp32 -> bf16 xh rows [N][128]; optional fused y2 (fp32) ------------
__global__ void split_kernel(const float* __restrict__ src, unsigned short* __restrict__ dst,
                             float* __restrict__ y2 /* nullptr to skip */) {
    size_t t = (size_t)blockIdx.x * 256 + threadIdx.x;   // one per 4 elems
    size_t row = t >> 5;
    int kc = (int)(t & 31) * 4;
    float4 v = reinterpret_cast<const float4*>(src)[t];
    ushort4 h;
    h.x = f2bf_rne(v.x); h.y = f2bf_rne(v.y); h.z = f2bf_rne(v.z); h.w = f2bf_rne(v.w);
    *reinterpret_cast<ushort4*>(&dst[row * 128 + kc]) = h;

    if (y2 != nullptr) {
        // 32 consecutive threads own one row; reduce sum of squares (fp32)
        float s = fmaf(v.x, v.x, fmaf(v.y, v.y, fmaf(v.z, v.z, v.w * v.w)));
#pragma unroll
        for (int off = 16; off >= 1; off >>= 1) s += __shfl_xor(s, off);
        if ((t & 31) == 0) y2[row] = s;
    }
}

// ---- MFMA GEMM (plain bf16, K=128) + top-2 argmin epilogue --------------------
// 128x128 tile, 4 waves (2x2), each wave 64x64 via 4x4 mfma_f32_16x16x32_bf16.
// LDS tiles [128][64] bf16 per phase, XOR-swizzled 16B chunks.
__global__ __launch_bounds__(256) void gemm_mfma(
    const unsigned short* __restrict__ Aext,  // [B][N][128] bf16
    const unsigned short* __restrict__ Bext,
    const float* __restrict__ y2g,
    float* __restrict__ pv1, float* __restrict__ pv2, unsigned int* __restrict__ pidx)
{
    __shared__ short As[128 * 64];
    __shared__ short Bs[128 * 64];
    __shared__ float rv1[2][128];
    __shared__ float rv2[2][128];
    __shared__ unsigned int ri[2][128];

    const int tid  = threadIdx.x;
    const int lane = tid & 63;
    const int wid  = tid >> 6;
    const int wr   = wid >> 1, wc = wid & 1;
    const int l15  = lane & 15, l4 = lane >> 4;
    const int bm   = blockIdx.x;
    const int bnc  = blockIdx.y;
    const int b    = blockIdx.z;
    const int row0 = bm * 128, col0 = bnc * 128;

    const unsigned short* Abase = Aext + ((size_t)b * NPTS + row0) * 128;
    const unsigned short* Bbase = Bext + ((size_t)b * NPTS + col0) * 128;

    f32x4 acc[4][4];
#pragma unroll
    for (int i = 0; i < 4; ++i)
#pragma unroll
        for (int j = 0; j < 4; ++j) acc[i][j] = (f32x4)0.0f;

#pragma unroll
    for (int kk = 0; kk < 2; ++kk) {          // K halves: cols [0,64) and [64,128)
        __syncthreads();
        {
            const int ko = kk * 64;
#pragma unroll
            for (int it = 0; it < 4; ++it) {
                int flat = it * 256 + tid;    // 16B-chunk id 0..1023 (128 rows x 8 chunks)
                int r = flat >> 3, kc = flat & 7;
                int kcs = kc ^ (r & 7);       // inverse-swizzled source chunk
                const unsigned short* ga = Abase + (size_t)r * 128 + ko + kcs * 8;
                const unsigned short* gb = Bbase + (size_t)r * 128 + ko + kcs * 8;
                __builtin_amdgcn_global_load_lds((as1_uint*)ga, (as3_uint*)&As[flat * 8], 16, 0, 0);
                __builtin_amdgcn_global_load_lds((as1_uint*)gb, (as3_uint*)&Bs[flat * 8], 16, 0, 0);
            }
        }
        __syncthreads();
#pragma unroll
        for (int ks = 0; ks < 2; ++ks) {
            short8v a[4], bf[4];
#pragma unroll
            for (int i = 0; i < 4; ++i) {
                int ra = wr * 64 + i * 16 + l15;
                int ch = ks * 4 + l4;
                a[i] = *reinterpret_cast<const short8v*>(&As[ra * 64 + ((ch ^ (ra & 7)) << 3)]);
            }
#pragma unroll
            for (int j = 0; j < 4; ++j) {
                int rb = wc * 64 + j * 16 + l15;
                int ch = ks * 4 + l4;
                bf[j] = *reinterpret_cast<const short8v*>(&Bs[rb * 64 + ((ch ^ (rb & 7)) << 3)]);
            }
#pragma unroll
            for (int i = 0; i < 4; ++i)
#pragma unroll
                for (int j = 0; j < 4; ++j)
                    acc[i][j] = __builtin_amdgcn_mfma_f32_16x16x32_bf16(a[i], bf[j], acc[i][j], 0, 0, 0);
        }
    }

    const float* y2b = y2g + b * NPTS;
    float yv[4];
#pragma unroll
    for (int j = 0; j < 4; ++j) yv[j] = y2b[col0 + wc * 64 + j * 16 + l15];

#pragma unroll
    for (int i = 0; i < 4; ++i) {
#pragma unroll
        for (int q = 0; q < 4; ++q) {
            float v1 = INFINITY, v2 = INFINITY;
            unsigned int mi = 0u;
#pragma unroll
            for (int j = 0; j < 4; ++j) {
                const float v = fmaf(-2.0f, acc[i][j][q], yv[j]);
                const unsigned int m = (unsigned)(col0 + wc * 64 + j * 16 + l15);
                if (v < v1) { v2 = v1; v1 = v; mi = m; }
                else        { v2 = fminf(v2, v); }
            }
#pragma unroll
            for (int off = 1; off < 16; off <<= 1) {
                float o1 = __shfl_xor(v1, off);
                float o2 = __shfl_xor(v2, off);
                unsigned int oi = __shfl_xor(mi, off);
                if (o1 < v1 || (o1 == v1 && oi < mi)) { v2 = fminf(v1, o2); v1 = o1; mi = oi; }
                else                                  { v2 = fminf(v2, fminf(o1, o2)); }
            }
            if (l15 == 0) {
                const int rl = wr * 64 + i * 16 + l4 * 4 + q;
                rv1[wc][rl] = v1; rv2[wc][rl] = v2; ri[wc][rl] = mi;
            }
        }
    }
    __syncthreads();
    if (tid < 128) {
        float a1 = rv1[0][tid], a2 = rv2[0][tid];
        unsigned int ai = ri[0][tid];
        const float o1 = rv1[1][tid], o2 = rv2[1][tid];
        const unsigned int oi = ri[1][tid];
        if (o1 < a1 || (o1 == a1 && oi < ai)) { a2 = fminf(a1, o2); a1 = o1; ai = oi; }
        else                                  { a2 = fminf(a2, fminf(o1, o2)); }
        const size_t gr = (size_t)b * NPTS + row0 + tid;
        pv1[(size_t)bnc * NROWS + gr] = a1;
        pv2[(size_t)bnc * NROWS + gr] = a2;
        pidx[(size_t)bnc * NROWS + gr] = ai;
    }
}

// ---- merge the 64 column-tile partials; compact near-tie rows into a list -----
__global__ void resolve_kernel(const float* __restrict__ pv1, const float* __restrict__ pv2,
                               const unsigned int* __restrict__ pidx,
                               unsigned int* __restrict__ idxFinal, float* __restrict__ bestval,
                               unsigned int* __restrict__ flagList, unsigned int* __restrict__ flagCount)
{
    const int gr = blockIdx.x * 256 + threadIdx.x;
    float a1 = INFINITY, a2 = INFINITY;
    unsigned int ai = 0u;
    for (int cs = 0; cs < NCOLT; ++cs) {
        const float o1 = pv1[(size_t)cs * NROWS + gr];
        const float o2 = pv2[(size_t)cs * NROWS + gr];
        const unsigned int oi = pidx[(size_t)cs * NROWS + gr];
        if (o1 < a1 || (o1 == a1 && oi < ai)) { a2 = fminf(a1, o2); a1 = o1; ai = oi; }
        else                                  { a2 = fminf(a2, fminf(o1, o2)); }
    }
    idxFinal[gr] = ai;
    bestval[gr] = a1;
    if (a2 - a1 < EPSGAP) {
        unsigned int pos = atomicAdd(flagCount, 1u);
        flagList[pos] = (unsigned int)gr;
    }
}

// ---- candidate-window fp64 recheck (fixed grid, grid-strides the flag list) ---
__global__ __launch_bounds__(256) void recheck_kernel(
    const float* __restrict__ f0, const float* __restrict__ f1,
    const float* __restrict__ pv1, const float* __restrict__ pv2,
    const unsigned int* __restrict__ pidx, const float* __restrict__ bestval,
    const unsigned int* __restrict__ flagList, const unsigned int* __restrict__ flagCount,
    unsigned int* __restrict__ idxFinal)
{
    __shared__ float xrow[DDIM];
    __shared__ unsigned int cand[RCAP];
    __shared__ int ncand;
    __shared__ double redv[256];
    __shared__ unsigned int redi[256];

    const int tid = threadIdx.x;
    const unsigned int nflag = *flagCount;

    for (unsigned int li = blockIdx.x; li < nflag; li += gridDim.x) {
        const int gr = (int)flagList[li];
        const int b = gr >> 13, n = gr & (NPTS - 1);
        const float W = bestval[gr] + EPSGAP;

        if (tid == 0) ncand = 0;
        if (tid < DDIM) xrow[tid] = f0[((size_t)b * NPTS + n) * DDIM + tid];
        __syncthreads();

        if (tid < NCOLT) {
            const size_t base = (size_t)tid * NROWS + gr;
            const float t1 = pv1[base];
            if (t1 <= W) {
                if (pv2[base] <= W) {
                    int p = atomicAdd(&ncand, 128);
                    if (p + 128 <= RCAP)
                        for (int c = 0; c < 128; ++c) cand[p + c] = (unsigned)(tid * 128 + c);
                } else {
                    int p = atomicAdd(&ncand, 1);
                    if (p < RCAP) cand[p] = pidx[base];
                }
            }
        }
        __syncthreads();

        const int nc = ncand;
        double bv = 1e300;
        unsigned int bi = 0xFFFFFFFFu;
        if (nc <= RCAP) {
            for (int c = tid; c < nc; c += 256) {
                const unsigned int m = cand[c];
                const float4* ypv = reinterpret_cast<const float4*>(f1 + ((size_t)b * NPTS + m) * DDIM);
                const float4* xpv = reinterpret_cast<const float4*>(xrow);
                double s0 = 0.0, s1 = 0.0, s2 = 0.0, s3 = 0.0;
#pragma unroll 8
                for (int k4 = 0; k4 < DDIM / 4; ++k4) {
                    const float4 y = ypv[k4];
                    const float4 x = xpv[k4];
                    s0 = fma((double)y.x, (double)y.x - 2.0 * (double)x.x, s0);
                    s1 = fma((double)y.y, (double)y.y - 2.0 * (double)x.y, s1);
                    s2 = fma((double)y.z, (double)y.z - 2.0 * (double)x.z, s2);
                    s3 = fma((double)y.w, (double)y.w - 2.0 * (double)x.w, s3);
                }
                const double v = (s0 + s1) + (s2 + s3);
                if (v < bv || (v == bv && m < bi)) { bv = v; bi = m; }
            }
        } else {
            for (int m = tid; m < NPTS; m += 256) {
                const float4* ypv = reinterpret_cast<const float4*>(f1 + ((size_t)b * NPTS + m) * DDIM);
                const float4* xpv = reinterpret_cast<const float4*>(xrow);
                double s0 = 0.0, s1 = 0.0, s2 = 0.0, s3 = 0.0;
#pragma unroll 4
                for (int k4 = 0; k4 < DDIM / 4; ++k4) {
                    const float4 y = ypv[k4];
                    const float4 x = xpv[k4];
                    s0 = fma((double)y.x, (double)y.x - 2.0 * (double)x.x, s0);
                    s1 = fma((double)y.y, (double)y.y - 2.0 * (double)x.y, s1);
                    s2 = fma((double)y.z, (double)y.z - 2.0 * (double)x.z, s2);
                    s3 = fma((double)y.w, (double)y.w - 2.0 * (double)x.w, s3);
                }
                const double v = (s0 + s1) + (s2 + s3);
                if (v < bv || (v == bv && (unsigned)m < bi)) { bv = v; bi = (unsigned)m; }
            }
        }
        redv[tid] = bv; redi[tid] = bi;
        __syncthreads();
        for (int s = 128; s >= 1; s >>= 1) {
            if (tid < s) {
                const double ov = redv[tid + s]; const unsigned int oi = redi[tid + s];
                if (ov < redv[tid] || (ov == redv[tid] && oi < redi[tid])) { redv[tid] = ov; redi[tid] = oi; }
            }
            __syncthreads();
        }
        if (tid == 0) idxFinal[gr] = redi[0];
        __syncthreads();
    }
}

// ---- fused zero-fill + one-hot + tail: one block per output row ---------------
// Contiguous 32 KB zero region per block (memset-like streaming), then patch.
__global__ __launch_bounds__(256) void writeout_kernel(const unsigned int* __restrict__ idxFinal,
                                                       float* __restrict__ out)
{
    const int gr = blockIdx.x;
    float4* o4 = reinterpret_cast<float4*>(out + (size_t)gr * NPTS);
    const float4 z = {0.0f, 0.0f, 0.0f, 0.0f};
#pragma unroll
    for (int it = 0; it < 8; ++it) o4[it * 256 + threadIdx.x] = z;
    __syncthreads();
    if (threadIdx.x == 0) {
        const unsigned int idx = idxFinal[gr];
        out[(size_t)gr * NPTS + idx] = 1.0f;
        out[(size_t)BATCH * NPTS * NPTS + gr] = (float)idx;
    }
}

extern "C" void kernel_launch(void* const* d_in, const int* in_sizes, int n_in,
                              void* d_out, int out_size, void* d_ws, size_t ws_size,
                              hipStream_t stream)
{
    const float* f0 = (const float*)d_in[0];
    const float* f1 = (const float*)d_in[1];
    float* out = (float*)d_out;

    // ws layout (bytes): Aext 4.19M | Bext 4.19M | y2 64K | pv1 4.19M | pv2 4.19M
    //                    | pidx 4.19M | idxFinal 64K | bestval 64K | flagList 64K
    //                    | flagCount 4  (~17.2 MB)
    char* wsb = (char*)d_ws;
    unsigned short* Aext = (unsigned short*)wsb;                  wsb += (size_t)BATCH * NPTS * 128 * 2;
    unsigned short* Bext = (unsigned short*)wsb;                  wsb += (size_t)BATCH * NPTS * 128 * 2;
    float* y2            = (float*)wsb;                           wsb += (size_t)NROWS * 4;
    float* pv1           = (float*)wsb;                           wsb += (size_t)NCOLT * NROWS * 4;
    float* pv2           = (float*)wsb;                           wsb += (size_t)NCOLT * NROWS * 4;
    unsigned int* pidx   = (unsigned int*)wsb;                    wsb += (size_t)NCOLT * NROWS * 4;
    unsigned int* idxFinal = (unsigned int*)wsb;                  wsb += (size_t)NROWS * 4;
    float* bestval       = (float*)wsb;                           wsb += (size_t)NROWS * 4;
    unsigned int* flagList = (unsigned int*)wsb;                  wsb += (size_t)NROWS * 4;
    unsigned int* flagCount = (unsigned int*)wsb;

    hipMemsetAsync(flagCount, 0, 4, stream);

    split_kernel<<<(BATCH * NPTS * 32) / 256, 256, 0, stream>>>(f0, Aext, nullptr);
    split_kernel<<<(BATCH * NPTS * 32) / 256, 256, 0, stream>>>(f1, Bext, y2);
    gemm_mfma<<<dim3(NPTS / 128, NPTS / 128, BATCH), 256, 0, stream>>>(Aext, Bext, y2, pv1, pv2, pidx);
    resolve_kernel<<<NROWS / 256, 256, 0, stream>>>(pv1, pv2, pidx, idxFinal, bestval, flagList, flagCount);
    recheck_kernel<<<1024, 256, 0, stream>>>(f0, f1, pv1, pv2, pidx, bestval, flagList, flagCount, idxFinal);
    writeout_kernel<<<NROWS, 256, 0, stream>>>(idxFinal, out);
}

// Round 6
// 356.941 us; speedup vs baseline: 1.0335x; 1.0335x over previous
//
#include <hip/hip_runtime.h>
#include <cstdint>
#include <cstddef>

#define NPTS 8192
#define DDIM 128
#define BATCH 2
#define NROWS (BATCH * NPTS)
#define EPSGAP 4.0f   // hard bound: 2*max|bf16 dot err| <= ~3.2 (Cauchy-Schwarz), +margin
#define NCOLT 64      // 8192 / 128 column tiles (partials per row)
#define RCAP 2048     // candidate-list capacity in recheck

typedef __attribute__((ext_vector_type(8))) short short8v;
typedef __attribute__((ext_vector_type(4))) float f32x4;

typedef __attribute__((address_space(3))) unsigned int as3_uint;
typedef const __attribute__((address_space(1))) unsigned int as1_uint;

static __device__ __forceinline__ unsigned short f2bf_rne(float x) {
    unsigned int u = __float_as_uint(x);
    unsigned int r = (u + 0x7FFFu + ((u >> 16) & 1u)) >> 16;
    return (unsigned short)r;
}

// ---- split fp32 -> bf16 xh rows [N][128]; optional fused y2 (fp32) ------------
__global__ void split_kernel(const float* __restrict__ src, unsigned short* __restrict__ dst,
                             float* __restrict__ y2 /* nullptr to skip */) {
    size_t t = (size_t)blockIdx.x * 256 + threadIdx.x;   // one per 4 elems
    size_t row = t >> 5;
    int kc = (int)(t & 31) * 4;
    float4 v = reinterpret_cast<const float4*>(src)[t];
    ushort4 h;
    h.x = f2bf_rne(v.x); h.y = f2bf_rne(v.y); h.z = f2bf_rne(v.z); h.w = f2bf_rne(v.w);
    *reinterpret_cast<ushort4*>(&dst[row * 128 + kc]) = h;

    if (y2 != nullptr) {
        // 32 consecutive threads own one row; reduce sum of squares (fp32)
        float s = fmaf(v.x, v.x, fmaf(v.y, v.y, fmaf(v.z, v.z, v.w * v.w)));
#pragma unroll
        for (int off = 16; off >= 1; off >>= 1) s += __shfl_xor(s, off);
        if ((t & 31) == 0) y2[row] = s;
    }
}

// ---- MFMA GEMM (plain bf16, K=128) + top-2 argmin epilogue --------------------
// 128x128 tile, 4 waves (2x2), each wave 64x64 via 4x4 mfma_f32_16x16x32_bf16.
// LDS tiles [128][64] bf16 per phase, XOR-swizzled 16B chunks.
__global__ __launch_bounds__(256) void gemm_mfma(
    const unsigned short* __restrict__ Aext,  // [B][N][128] bf16
    const unsigned short* __restrict__ Bext,
    const float* __restrict__ y2g,
    float* __restrict__ pv1, float* __restrict__ pv2, unsigned int* __restrict__ pidx)
{
    __shared__ short As[128 * 64];
    __shared__ short Bs[128 * 64];
    __shared__ float rv1[2][128];
    __shared__ float rv2[2][128];
    __shared__ unsigned int ri[2][128];

    const int tid  = threadIdx.x;
    const int lane = tid & 63;
    const int wid  = tid >> 6;
    const int wr   = wid >> 1, wc = wid & 1;
    const int l15  = lane & 15, l4 = lane >> 4;
    const int bm   = blockIdx.x;
    const int bnc  = blockIdx.y;
    const int b    = blockIdx.z;
    const int row0 = bm * 128, col0 = bnc * 128;

    const unsigned short* Abase = Aext + ((size_t)b * NPTS + row0) * 128;
    const unsigned short* Bbase = Bext + ((size_t)b * NPTS + col0) * 128;

    f32x4 acc[4][4];
#pragma unroll
    for (int i = 0; i < 4; ++i)
#pragma unroll
        for (int j = 0; j < 4; ++j) acc[i][j] = (f32x4)0.0f;

#pragma unroll
    for (int kk = 0; kk < 2; ++kk) {          // K halves: cols [0,64) and [64,128)
        __syncthreads();
        {
            const int ko = kk * 64;
#pragma unroll
            for (int it = 0; it < 4; ++it) {
                int flat = it * 256 + tid;    // 16B-chunk id 0..1023 (128 rows x 8 chunks)
                int r = flat >> 3, kc = flat & 7;
                int kcs = kc ^ (r & 7);       // inverse-swizzled source chunk
                const unsigned short* ga = Abase + (size_t)r * 128 + ko + kcs * 8;
                const unsigned short* gb = Bbase + (size_t)r * 128 + ko + kcs * 8;
                __builtin_amdgcn_global_load_lds((as1_uint*)ga, (as3_uint*)&As[flat * 8], 16, 0, 0);
                __builtin_amdgcn_global_load_lds((as1_uint*)gb, (as3_uint*)&Bs[flat * 8], 16, 0, 0);
            }
        }
        __syncthreads();
#pragma unroll
        for (int ks = 0; ks < 2; ++ks) {
            short8v a[4], bf[4];
#pragma unroll
            for (int i = 0; i < 4; ++i) {
                int ra = wr * 64 + i * 16 + l15;
                int ch = ks * 4 + l4;
                a[i] = *reinterpret_cast<const short8v*>(&As[ra * 64 + ((ch ^ (ra & 7)) << 3)]);
            }
#pragma unroll
            for (int j = 0; j < 4; ++j) {
                int rb = wc * 64 + j * 16 + l15;
                int ch = ks * 4 + l4;
                bf[j] = *reinterpret_cast<const short8v*>(&Bs[rb * 64 + ((ch ^ (rb & 7)) << 3)]);
            }
#pragma unroll
            for (int i = 0; i < 4; ++i)
#pragma unroll
                for (int j = 0; j < 4; ++j)
                    acc[i][j] = __builtin_amdgcn_mfma_f32_16x16x32_bf16(a[i], bf[j], acc[i][j], 0, 0, 0);
        }
    }

    const float* y2b = y2g + b * NPTS;
    float yv[4];
#pragma unroll
    for (int j = 0; j < 4; ++j) yv[j] = y2b[col0 + wc * 64 + j * 16 + l15];

#pragma unroll
    for (int i = 0; i < 4; ++i) {
#pragma unroll
        for (int q = 0; q < 4; ++q) {
            float v1 = INFINITY, v2 = INFINITY;
            unsigned int mi = 0u;
#pragma unroll
            for (int j = 0; j < 4; ++j) {
                const float v = fmaf(-2.0f, acc[i][j][q], yv[j]);
                const unsigned int m = (unsigned)(col0 + wc * 64 + j * 16 + l15);
                if (v < v1) { v2 = v1; v1 = v; mi = m; }
                else        { v2 = fminf(v2, v); }
            }
#pragma unroll
            for (int off = 1; off < 16; off <<= 1) {
                float o1 = __shfl_xor(v1, off);
                float o2 = __shfl_xor(v2, off);
                unsigned int oi = __shfl_xor(mi, off);
                if (o1 < v1 || (o1 == v1 && oi < mi)) { v2 = fminf(v1, o2); v1 = o1; mi = oi; }
                else                                  { v2 = fminf(v2, fminf(o1, o2)); }
            }
            if (l15 == 0) {
                const int rl = wr * 64 + i * 16 + l4 * 4 + q;
                rv1[wc][rl] = v1; rv2[wc][rl] = v2; ri[wc][rl] = mi;
            }
        }
    }
    __syncthreads();
    if (tid < 128) {
        float a1 = rv1[0][tid], a2 = rv2[0][tid];
        unsigned int ai = ri[0][tid];
        const float o1 = rv1[1][tid], o2 = rv2[1][tid];
        const unsigned int oi = ri[1][tid];
        if (o1 < a1 || (o1 == a1 && oi < ai)) { a2 = fminf(a1, o2); a1 = o1; ai = oi; }
        else                                  { a2 = fminf(a2, fminf(o1, o2)); }
        const size_t gr = (size_t)b * NPTS + row0 + tid;
        pv1[(size_t)bnc * NROWS + gr] = a1;
        pv2[(size_t)bnc * NROWS + gr] = a2;
        pidx[(size_t)bnc * NROWS + gr] = ai;
    }
}

// ---- merge the 64 column-tile partials; compact near-tie rows into a list -----
__global__ void resolve_kernel(const float* __restrict__ pv1, const float* __restrict__ pv2,
                               const unsigned int* __restrict__ pidx,
                               unsigned int* __restrict__ idxFinal, float* __restrict__ bestval,
                               unsigned int* __restrict__ flagList, unsigned int* __restrict__ flagCount)
{
    const int gr = blockIdx.x * 256 + threadIdx.x;
    float a1 = INFINITY, a2 = INFINITY;
    unsigned int ai = 0u;
    for (int cs = 0; cs < NCOLT; ++cs) {
        const float o1 = pv1[(size_t)cs * NROWS + gr];
        const float o2 = pv2[(size_t)cs * NROWS + gr];
        const unsigned int oi = pidx[(size_t)cs * NROWS + gr];
        if (o1 < a1 || (o1 == a1 && oi < ai)) { a2 = fminf(a1, o2); a1 = o1; ai = oi; }
        else                                  { a2 = fminf(a2, fminf(o1, o2)); }
    }
    idxFinal[gr] = ai;
    bestval[gr] = a1;
    if (a2 - a1 < EPSGAP) {
        unsigned int pos = atomicAdd(flagCount, 1u);
        flagList[pos] = (unsigned int)gr;
    }
}

// ---- candidate-window fp64 recheck (fixed grid, grid-strides the flag list) ---
__global__ __launch_bounds__(256) void recheck_kernel(
    const float* __restrict__ f0, const float* __restrict__ f1,
    const float* __restrict__ pv1, const float* __restrict__ pv2,
    const unsigned int* __restrict__ pidx, const float* __restrict__ bestval,
    const unsigned int* __restrict__ flagList, const unsigned int* __restrict__ flagCount,
    unsigned int* __restrict__ idxFinal)
{
    __shared__ float xrow[DDIM];
    __shared__ unsigned int cand[RCAP];
    __shared__ int ncand;
    __shared__ double redv[256];
    __shared__ unsigned int redi[256];

    const int tid = threadIdx.x;
    const unsigned int nflag = *flagCount;

    for (unsigned int li = blockIdx.x; li < nflag; li += gridDim.x) {
        const int gr = (int)flagList[li];
        const int b = gr >> 13, n = gr & (NPTS - 1);
        const float W = bestval[gr] + EPSGAP;

        if (tid == 0) ncand = 0;
        if (tid < DDIM) xrow[tid] = f0[((size_t)b * NPTS + n) * DDIM + tid];
        __syncthreads();

        if (tid < NCOLT) {
            const size_t base = (size_t)tid * NROWS + gr;
            const float t1 = pv1[base];
            if (t1 <= W) {
                if (pv2[base] <= W) {
                    int p = atomicAdd(&ncand, 128);
                    if (p + 128 <= RCAP)
                        for (int c = 0; c < 128; ++c) cand[p + c] = (unsigned)(tid * 128 + c);
                } else {
                    int p = atomicAdd(&ncand, 1);
                    if (p < RCAP) cand[p] = pidx[base];
                }
            }
        }
        __syncthreads();

        const int nc = ncand;
        double bv = 1e300;
        unsigned int bi = 0xFFFFFFFFu;
        if (nc <= RCAP) {
            for (int c = tid; c < nc; c += 256) {
                const unsigned int m = cand[c];
                const float4* ypv = reinterpret_cast<const float4*>(f1 + ((size_t)b * NPTS + m) * DDIM);
                const float4* xpv = reinterpret_cast<const float4*>(xrow);
                double s0 = 0.0, s1 = 0.0, s2 = 0.0, s3 = 0.0;
#pragma unroll 8
                for (int k4 = 0; k4 < DDIM / 4; ++k4) {
                    const float4 y = ypv[k4];
                    const float4 x = xpv[k4];
                    s0 = fma((double)y.x, (double)y.x - 2.0 * (double)x.x, s0);
                    s1 = fma((double)y.y, (double)y.y - 2.0 * (double)x.y, s1);
                    s2 = fma((double)y.z, (double)y.z - 2.0 * (double)x.z, s2);
                    s3 = fma((double)y.w, (double)y.w - 2.0 * (double)x.w, s3);
                }
                const double v = (s0 + s1) + (s2 + s3);
                if (v < bv || (v == bv && m < bi)) { bv = v; bi = m; }
            }
        } else {
            for (int m = tid; m < NPTS; m += 256) {
                const float4* ypv = reinterpret_cast<const float4*>(f1 + ((size_t)b * NPTS + m) * DDIM);
                const float4* xpv = reinterpret_cast<const float4*>(xrow);
                double s0 = 0.0, s1 = 0.0, s2 = 0.0, s3 = 0.0;
#pragma unroll 4
                for (int k4 = 0; k4 < DDIM / 4; ++k4) {
                    const float4 y = ypv[k4];
                    const float4 x = xpv[k4];
                    s0 = fma((double)y.x, (double)y.x - 2.0 * (double)x.x, s0);
                    s1 = fma((double)y.y, (double)y.y - 2.0 * (double)x.y, s1);
                    s2 = fma((double)y.z, (double)y.z - 2.0 * (double)x.z, s2);
                    s3 = fma((double)y.w, (double)y.w - 2.0 * (double)x.w, s3);
                }
                const double v = (s0 + s1) + (s2 + s3);
                if (v < bv || (v == bv && (unsigned)m < bi)) { bv = v; bi = (unsigned)m; }
            }
        }
        redv[tid] = bv; redi[tid] = bi;
        __syncthreads();
        for (int s = 128; s >= 1; s >>= 1) {
            if (tid < s) {
                const double ov = redv[tid + s]; const unsigned int oi = redi[tid + s];
                if (ov < redv[tid] || (ov == redv[tid] && oi < redi[tid])) { redv[tid] = ov; redi[tid] = oi; }
            }
            __syncthreads();
        }
        if (tid == 0) idxFinal[gr] = redi[0];
        __syncthreads();
    }
}

// ---- write one-hot 1.0s and idx-as-float tail (d_out pre-zeroed by memset) ----
__global__ void scatter_kernel(const unsigned int* __restrict__ idxFinal, float* __restrict__ out) {
    const int gr = blockIdx.x * 256 + threadIdx.x;
    const unsigned int idx = idxFinal[gr];
    out[(size_t)gr * NPTS + idx] = 1.0f;
    out[(size_t)BATCH * NPTS * NPTS + gr] = (float)idx;
}

extern "C" void kernel_launch(void* const* d_in, const int* in_sizes, int n_in,
                              void* d_out, int out_size, void* d_ws, size_t ws_size,
                              hipStream_t stream)
{
    const float* f0 = (const float*)d_in[0];
    const float* f1 = (const float*)d_in[1];
    float* out = (float*)d_out;

    // ws layout (bytes): Aext 4.19M | Bext 4.19M | y2 64K | pv1 4.19M | pv2 4.19M
    //                    | pidx 4.19M | idxFinal 64K | bestval 64K | flagList 64K
    //                    | flagCount 4  (~17.2 MB)
    char* wsb = (char*)d_ws;
    unsigned short* Aext = (unsigned short*)wsb;                  wsb += (size_t)BATCH * NPTS * 128 * 2;
    unsigned short* Bext = (unsigned short*)wsb;                  wsb += (size_t)BATCH * NPTS * 128 * 2;
    float* y2            = (float*)wsb;                           wsb += (size_t)NROWS * 4;
    float* pv1           = (float*)wsb;                           wsb += (size_t)NCOLT * NROWS * 4;
    float* pv2           = (float*)wsb;                           wsb += (size_t)NCOLT * NROWS * 4;
    unsigned int* pidx   = (unsigned int*)wsb;                    wsb += (size_t)NCOLT * NROWS * 4;
    unsigned int* idxFinal = (unsigned int*)wsb;                  wsb += (size_t)NROWS * 4;
    float* bestval       = (float*)wsb;                           wsb += (size_t)NROWS * 4;
    unsigned int* flagList = (unsigned int*)wsb;                  wsb += (size_t)NROWS * 4;
    unsigned int* flagCount = (unsigned int*)wsb;

    // rocclr fill path sustains ~6.75 TB/s (measured on the harness poison fill) —
    // use it for the 537 MB zero pass instead of a custom store kernel (R4/R5 both
    // measured ~2.5-2.8 TB/s effective for plain-store fill kernels).
    hipMemsetAsync(d_out, 0, (size_t)out_size * sizeof(float), stream);
    hipMemsetAsync(flagCount, 0, 4, stream);

    split_kernel<<<(BATCH * NPTS * 32) / 256, 256, 0, stream>>>(f0, Aext, nullptr);
    split_kernel<<<(BATCH * NPTS * 32) / 256, 256, 0, stream>>>(f1, Bext, y2);
    gemm_mfma<<<dim3(NPTS / 128, NPTS / 128, BATCH), 256, 0, stream>>>(Aext, Bext, y2, pv1, pv2, pidx);
    resolve_kernel<<<NROWS / 256, 256, 0, stream>>>(pv1, pv2, pidx, idxFinal, bestval, flagList, flagCount);
    recheck_kernel<<<1024, 256, 0, stream>>>(f0, f1, pv1, pv2, pidx, bestval, flagList, flagCount, idxFinal);
    scatter_kernel<<<NROWS / 256, 256, 0, stream>>>(idxFinal, out);
}

// Round 7
// 243.570 us; speedup vs baseline: 1.5145x; 1.4655x over previous
//
#include <hip/hip_runtime.h>
#include <hip/hip_fp16.h>
#include <cstdint>
#include <cstddef>

#define NPTS 8192
#define DDIM 128
#define BATCH 2
#define NROWS (BATCH * NPTS)
#define EPSGAP 1.0f   // certified: 2*max dist err (f16, 2^-11 u) <= 0.77 < 1.0
#define NCOLT 64      // 8192 / 128 column tiles (partials per row)
#define WCAP 512      // per-wave candidate capacity in recheck

typedef __attribute__((ext_vector_type(8))) _Float16 half8v;
typedef __attribute__((ext_vector_type(4))) float f32x4;

typedef __attribute__((address_space(3))) unsigned int as3_uint;
typedef const __attribute__((address_space(1))) unsigned int as1_uint;

// ---- split fp32 -> f16 rows [N][128]; fused y2 (fp32) and flagCount zero -----
__global__ void split_kernel(const float* __restrict__ src, unsigned short* __restrict__ dst,
                             float* __restrict__ y2 /* nullptr to skip */,
                             unsigned int* __restrict__ flagCount /* nullptr to skip */) {
    if (flagCount != nullptr && blockIdx.x == 0 && threadIdx.x == 0) *flagCount = 0u;
    size_t t = (size_t)blockIdx.x * 256 + threadIdx.x;   // one per 4 elems
    size_t row = t >> 5;
    int kc = (int)(t & 31) * 4;
    float4 v = reinterpret_cast<const float4*>(src)[t];
    ushort4 h;
    h.x = __half_as_ushort(__float2half(v.x));
    h.y = __half_as_ushort(__float2half(v.y));
    h.z = __half_as_ushort(__float2half(v.z));
    h.w = __half_as_ushort(__float2half(v.w));
    *reinterpret_cast<ushort4*>(&dst[row * 128 + kc]) = h;

    if (y2 != nullptr) {
        // 32 consecutive threads own one row; reduce sum of squares (fp32)
        float s = fmaf(v.x, v.x, fmaf(v.y, v.y, fmaf(v.z, v.z, v.w * v.w)));
#pragma unroll
        for (int off = 16; off >= 1; off >>= 1) s += __shfl_xor(s, off);
        if ((t & 31) == 0) y2[row] = s;
    }
}

// ---- MFMA GEMM (f16, K=128) + top-2 argmin epilogue + streaming output zero ---
// 128x128 tile, 4 waves (2x2), each wave 64x64 via 4x4 mfma_f32_16x16x32_f16.
// LDS tiles [128][64] f16 per phase, XOR-swizzled 16B chunks.
// Epilogue: each block zeroes its 64 KB slice of d_out with NT stores — the
// 512 MB zero pass rides the GEMM's idle write BW (replaces a serial memset).
__global__ __launch_bounds__(256) void gemm_mfma(
    const unsigned short* __restrict__ Aext,  // [B][N][128] f16 bits
    const unsigned short* __restrict__ Bext,
    const float* __restrict__ y2g,
    float* __restrict__ pv1, float* __restrict__ pv2, unsigned int* __restrict__ pidx,
    float* __restrict__ outZero)
{
    __shared__ __align__(16) short As[128 * 64];
    __shared__ __align__(16) short Bs[128 * 64];
    __shared__ float rv1[2][128];
    __shared__ float rv2[2][128];
    __shared__ unsigned int ri[2][128];

    const int tid  = threadIdx.x;
    const int lane = tid & 63;
    const int wid  = tid >> 6;
    const int wr   = wid >> 1, wc = wid & 1;
    const int l15  = lane & 15, l4 = lane >> 4;
    const int bm   = blockIdx.x;
    const int bnc  = blockIdx.y;
    const int b    = blockIdx.z;
    const int row0 = bm * 128, col0 = bnc * 128;

    const unsigned short* Abase = Aext + ((size_t)b * NPTS + row0) * 128;
    const unsigned short* Bbase = Bext + ((size_t)b * NPTS + col0) * 128;

    f32x4 acc[4][4];
#pragma unroll
    for (int i = 0; i < 4; ++i)
#pragma unroll
        for (int j = 0; j < 4; ++j) acc[i][j] = (f32x4)0.0f;

#pragma unroll
    for (int kk = 0; kk < 2; ++kk) {          // K halves: cols [0,64) and [64,128)
        __syncthreads();
        {
            const int ko = kk * 64;
#pragma unroll
            for (int it = 0; it < 4; ++it) {
                int flat = it * 256 + tid;    // 16B-chunk id 0..1023 (128 rows x 8 chunks)
                int r = flat >> 3, kc = flat & 7;
                int kcs = kc ^ (r & 7);       // inverse-swizzled source chunk
                const unsigned short* ga = Abase + (size_t)r * 128 + ko + kcs * 8;
                const unsigned short* gb = Bbase + (size_t)r * 128 + ko + kcs * 8;
                __builtin_amdgcn_global_load_lds((as1_uint*)ga, (as3_uint*)&As[flat * 8], 16, 0, 0);
                __builtin_amdgcn_global_load_lds((as1_uint*)gb, (as3_uint*)&Bs[flat * 8], 16, 0, 0);
            }
        }
        __syncthreads();
#pragma unroll
        for (int ks = 0; ks < 2; ++ks) {
            half8v a[4], bf[4];
#pragma unroll
            for (int i = 0; i < 4; ++i) {
                int ra = wr * 64 + i * 16 + l15;
                int ch = ks * 4 + l4;
                a[i] = *reinterpret_cast<const half8v*>(&As[ra * 64 + ((ch ^ (ra & 7)) << 3)]);
            }
#pragma unroll
            for (int j = 0; j < 4; ++j) {
                int rb = wc * 64 + j * 16 + l15;
                int ch = ks * 4 + l4;
                bf[j] = *reinterpret_cast<const half8v*>(&Bs[rb * 64 + ((ch ^ (rb & 7)) << 3)]);
            }
#pragma unroll
            for (int i = 0; i < 4; ++i)
#pragma unroll
                for (int j = 0; j < 4; ++j)
                    acc[i][j] = __builtin_amdgcn_mfma_f32_16x16x32_f16(a[i], bf[j], acc[i][j], 0, 0, 0);
        }
    }

    const float* y2b = y2g + b * NPTS;
    float yv[4];
#pragma unroll
    for (int j = 0; j < 4; ++j) yv[j] = y2b[col0 + wc * 64 + j * 16 + l15];

#pragma unroll
    for (int i = 0; i < 4; ++i) {
#pragma unroll
        for (int q = 0; q < 4; ++q) {
            float v1 = INFINITY, v2 = INFINITY;
            unsigned int mi = 0u;
#pragma unroll
            for (int j = 0; j < 4; ++j) {
                const float v = fmaf(-2.0f, acc[i][j][q], yv[j]);
                const unsigned int m = (unsigned)(col0 + wc * 64 + j * 16 + l15);
                if (v < v1) { v2 = v1; v1 = v; mi = m; }
                else        { v2 = fminf(v2, v); }
            }
#pragma unroll
            for (int off = 1; off < 16; off <<= 1) {
                float o1 = __shfl_xor(v1, off);
                float o2 = __shfl_xor(v2, off);
                unsigned int oi = __shfl_xor(mi, off);
                if (o1 < v1 || (o1 == v1 && oi < mi)) { v2 = fminf(v1, o2); v1 = o1; mi = oi; }
                else                                  { v2 = fminf(v2, fminf(o1, o2)); }
            }
            if (l15 == 0) {
                const int rl = wr * 64 + i * 16 + l4 * 4 + q;
                rv1[wc][rl] = v1; rv2[wc][rl] = v2; ri[wc][rl] = mi;
            }
        }
    }
    __syncthreads();
    if (tid < 128) {
        float a1 = rv1[0][tid], a2 = rv2[0][tid];
        unsigned int ai = ri[0][tid];
        const float o1 = rv1[1][tid], o2 = rv2[1][tid];
        const unsigned int oi = ri[1][tid];
        if (o1 < a1 || (o1 == a1 && oi < ai)) { a2 = fminf(a1, o2); a1 = o1; ai = oi; }
        else                                  { a2 = fminf(a2, fminf(o1, o2)); }
        const size_t gr = (size_t)b * NPTS + row0 + tid;
        pv1[(size_t)bnc * NROWS + gr] = a1;
        pv2[(size_t)bnc * NROWS + gr] = a2;
        pidx[(size_t)bnc * NROWS + gr] = ai;
    }

    // streaming zero of this block's 64 KB output slice (after all barriers;
    // fire-and-forget NT stores drain by kernel end, overlapping other blocks)
    {
        const int bid = bm + 64 * bnc + 4096 * b;   // 0..8191
        f32x4* o4 = reinterpret_cast<f32x4*>(outZero) + (size_t)bid * 4096;
        const f32x4 z = (f32x4)0.0f;
#pragma unroll
        for (int it = 0; it < 16; ++it)
            __builtin_nontemporal_store(z, &o4[it * 256 + tid]);
    }
}

// ---- merge the 64 column-tile partials; compact near-tie rows into a list -----
__global__ void resolve_kernel(const float* __restrict__ pv1, const float* __restrict__ pv2,
                               const unsigned int* __restrict__ pidx,
                               unsigned int* __restrict__ idxFinal, float* __restrict__ bestval,
                               unsigned int* __restrict__ flagList, unsigned int* __restrict__ flagCount)
{
    const int gr = blockIdx.x * 256 + threadIdx.x;
    float a1 = INFINITY, a2 = INFINITY;
    unsigned int ai = 0u;
    for (int cs = 0; cs < NCOLT; ++cs) {
        const float o1 = pv1[(size_t)cs * NROWS + gr];
        const float o2 = pv2[(size_t)cs * NROWS + gr];
        const unsigned int oi = pidx[(size_t)cs * NROWS + gr];
        if (o1 < a1 || (o1 == a1 && oi < ai)) { a2 = fminf(a1, o2); a1 = o1; ai = oi; }
        else                                  { a2 = fminf(a2, fminf(o1, o2)); }
    }
    idxFinal[gr] = ai;
    bestval[gr] = a1;
    if (a2 - a1 < EPSGAP) {
        unsigned int pos = atomicAdd(flagCount, 1u);
        flagList[pos] = (unsigned int)gr;
    }
}

// ---- candidate-window fp64 recheck: one WAVE per flagged row ------------------
// 4 independent waves per block, no __syncthreads; shuffle argmin reduce.
__global__ __launch_bounds__(256) void recheck_kernel(
    const float* __restrict__ f0, const float* __restrict__ f1,
    const float* __restrict__ pv1, const float* __restrict__ pv2,
    const unsigned int* __restrict__ pidx, const float* __restrict__ bestval,
    const unsigned int* __restrict__ flagList, const unsigned int* __restrict__ flagCount,
    unsigned int* __restrict__ idxFinal)
{
    __shared__ float xrow[4][DDIM];
    __shared__ unsigned int cand[4][WCAP];
    __shared__ int ncand[4];

    const int tid  = threadIdx.x;
    const int w    = tid >> 6;
    const int lane = tid & 63;
    const unsigned int nflag = *flagCount;
    const unsigned int slot0 = blockIdx.x * 4 + w;
    const unsigned int nslots = gridDim.x * 4;

    for (unsigned int li = slot0; li < nflag; li += nslots) {
        const int gr = (int)flagList[li];
        const int b = gr >> 13, n = gr & (NPTS - 1);
        const float W = bestval[gr] + EPSGAP;

        if (lane == 0) ncand[w] = 0;
        const float* xp = f0 + ((size_t)b * NPTS + n) * DDIM;
        xrow[w][lane]      = xp[lane];
        xrow[w][lane + 64] = xp[lane + 64];

        // screen: lane == tile index
        {
            const size_t base = (size_t)lane * NROWS + gr;
            const float t1 = pv1[base];
            if (t1 <= W) {
                if (pv2[base] <= W) {
                    int p = atomicAdd(&ncand[w], 128);
                    if (p + 128 <= WCAP)
                        for (int c = 0; c < 128; ++c) cand[w][p + c] = (unsigned)(lane * 128 + c);
                } else {
                    int p = atomicAdd(&ncand[w], 1);
                    if (p < WCAP) cand[w][p] = pidx[base];
                }
            }
        }
        asm volatile("s_waitcnt lgkmcnt(0)" ::: "memory");  // wave-local LDS drain

        const int nc = ncand[w];
        double bv = 1e300;
        unsigned int bi = 0xFFFFFFFFu;
        const float4* xpv = reinterpret_cast<const float4*>(xrow[w]);
        if (nc <= WCAP) {
            for (int c = lane; c < nc; c += 64) {
                const unsigned int m = cand[w][c];
                const float4* ypv = reinterpret_cast<const float4*>(f1 + ((size_t)b * NPTS + m) * DDIM);
                double s0 = 0.0, s1 = 0.0, s2 = 0.0, s3 = 0.0;
#pragma unroll 8
                for (int k4 = 0; k4 < DDIM / 4; ++k4) {
                    const float4 y = ypv[k4];
                    const float4 x = xpv[k4];
                    s0 = fma((double)y.x, (double)y.x - 2.0 * (double)x.x, s0);
                    s1 = fma((double)y.y, (double)y.y - 2.0 * (double)x.y, s1);
                    s2 = fma((double)y.z, (double)y.z - 2.0 * (double)x.z, s2);
                    s3 = fma((double)y.w, (double)y.w - 2.0 * (double)x.w, s3);
                }
                const double v = (s0 + s1) + (s2 + s3);
                if (v < bv || (v == bv && m < bi)) { bv = v; bi = m; }
            }
        } else {
            for (int m = lane; m < NPTS; m += 64) {
                const float4* ypv = reinterpret_cast<const float4*>(f1 + ((size_t)b * NPTS + m) * DDIM);
                double s0 = 0.0, s1 = 0.0, s2 = 0.0, s3 = 0.0;
#pragma unroll 4
                for (int k4 = 0; k4 < DDIM / 4; ++k4) {
                    const float4 y = ypv[k4];
                    const float4 x = xpv[k4];
                    s0 = fma((double)y.x, (double)y.x - 2.0 * (double)x.x, s0);
                    s1 = fma((double)y.y, (double)y.y - 2.0 * (double)x.y, s1);
                    s2 = fma((double)y.z, (double)y.z - 2.0 * (double)x.z, s2);
                    s3 = fma((double)y.w, (double)y.w - 2.0 * (double)x.w, s3);
                }
                const double v = (s0 + s1) + (s2 + s3);
                if (v < bv || (v == bv && (unsigned)m < bi)) { bv = v; bi = (unsigned)m; }
            }
        }
        // wave argmin reduce (exact doubles; first-occurrence tie-break)
#pragma unroll
        for (int off = 1; off < 64; off <<= 1) {
            const double ov = __shfl_xor(bv, off);
            const unsigned int oi = __shfl_xor(bi, off);
            if (ov < bv || (ov == bv && oi < bi)) { bv = ov; bi = oi; }
        }
        if (lane == 0) idxFinal[gr] = bi;
        asm volatile("s_waitcnt lgkmcnt(0)" ::: "memory");  // before LDS reuse next iter
    }
}

// ---- write one-hot 1.0s and idx-as-float tail (zeros written by gemm) ---------
__global__ void scatter_kernel(const unsigned int* __restrict__ idxFinal, float* __restrict__ out) {
    const int gr = blockIdx.x * 256 + threadIdx.x;
    const unsigned int idx = idxFinal[gr];
    out[(size_t)gr * NPTS + idx] = 1.0f;
    out[(size_t)BATCH * NPTS * NPTS + gr] = (float)idx;
}

extern "C" void kernel_launch(void* const* d_in, const int* in_sizes, int n_in,
                              void* d_out, int out_size, void* d_ws, size_t ws_size,
                              hipStream_t stream)
{
    const float* f0 = (const float*)d_in[0];
    const float* f1 = (const float*)d_in[1];
    float* out = (float*)d_out;

    // ws layout (bytes): Aext 4.19M | Bext 4.19M | y2 64K | pv1 4.19M | pv2 4.19M
    //                    | pidx 4.19M | idxFinal 64K | bestval 64K | flagList 64K
    //                    | flagCount 4  (~17.2 MB)
    char* wsb = (char*)d_ws;
    unsigned short* Aext = (unsigned short*)wsb;                  wsb += (size_t)BATCH * NPTS * 128 * 2;
    unsigned short* Bext = (unsigned short*)wsb;                  wsb += (size_t)BATCH * NPTS * 128 * 2;
    float* y2            = (float*)wsb;                           wsb += (size_t)NROWS * 4;
    float* pv1           = (float*)wsb;                           wsb += (size_t)NCOLT * NROWS * 4;
    float* pv2           = (float*)wsb;                           wsb += (size_t)NCOLT * NROWS * 4;
    unsigned int* pidx   = (unsigned int*)wsb;                    wsb += (size_t)NCOLT * NROWS * 4;
    unsigned int* idxFinal = (unsigned int*)wsb;                  wsb += (size_t)NROWS * 4;
    float* bestval       = (float*)wsb;                           wsb += (size_t)NROWS * 4;
    unsigned int* flagList = (unsigned int*)wsb;                  wsb += (size_t)NROWS * 4;
    unsigned int* flagCount = (unsigned int*)wsb;

    split_kernel<<<(BATCH * NPTS * 32) / 256, 256, 0, stream>>>(f0, Aext, nullptr, flagCount);
    split_kernel<<<(BATCH * NPTS * 32) / 256, 256, 0, stream>>>(f1, Bext, y2, nullptr);
    gemm_mfma<<<dim3(NPTS / 128, NPTS / 128, BATCH), 256, 0, stream>>>(Aext, Bext, y2, pv1, pv2, pidx, out);
    resolve_kernel<<<NROWS / 256, 256, 0, stream>>>(pv1, pv2, pidx, idxFinal, bestval, flagList, flagCount);
    recheck_kernel<<<512, 256, 0, stream>>>(f0, f1, pv1, pv2, pidx, bestval, flagList, flagCount, idxFinal);
    scatter_kernel<<<NROWS / 256, 256, 0, stream>>>(idxFinal, out);
}

// Round 8
// 207.523 us; speedup vs baseline: 1.7776x; 1.1737x over previous
//
#include <hip/hip_runtime.h>
#include <hip/hip_fp16.h>
#include <cstdint>
#include <cstddef>

#define NPTS 8192
#define DDIM 128
#define BATCH 2
#define NROWS (BATCH * NPTS)
#define EPSGAP 1.0f   // certified: 2*max dist err (f16, 2^-11 u) <= 0.77 < 1.0
#define NCOLT 64      // 8192 / 128 column tiles (partials per row)
#define WCAP 512      // per-wave candidate capacity in recheck

typedef __attribute__((ext_vector_type(8))) _Float16 half8v;
typedef __attribute__((ext_vector_type(4))) float f32x4;

typedef __attribute__((address_space(3))) unsigned int as3_uint;
typedef const __attribute__((address_space(1))) unsigned int as1_uint;

// ---- fused split: fp32 -> f16 rows for BOTH inputs; y2 for f1; flagCount=0 ----
__global__ void split_kernel(const float* __restrict__ f0, const float* __restrict__ f1,
                             unsigned short* __restrict__ Aext, unsigned short* __restrict__ Bext,
                             float* __restrict__ y2, unsigned int* __restrict__ flagCount) {
    if (blockIdx.x == 0 && threadIdx.x == 0) *flagCount = 0u;
    const unsigned half = gridDim.x >> 1;
    const bool isB = blockIdx.x >= half;
    const float* src = isB ? f1 : f0;
    unsigned short* dst = isB ? Bext : Aext;
    size_t t = (size_t)(blockIdx.x - (isB ? half : 0)) * 256 + threadIdx.x;  // one per 4 elems
    size_t row = t >> 5;
    int kc = (int)(t & 31) * 4;
    float4 v = reinterpret_cast<const float4*>(src)[t];
    ushort4 h;
    h.x = __half_as_ushort(__float2half(v.x));
    h.y = __half_as_ushort(__float2half(v.y));
    h.z = __half_as_ushort(__float2half(v.z));
    h.w = __half_as_ushort(__float2half(v.w));
    *reinterpret_cast<ushort4*>(&dst[row * 128 + kc]) = h;

    if (isB) {
        // 32 consecutive threads own one row; reduce sum of squares (fp32)
        float s = fmaf(v.x, v.x, fmaf(v.y, v.y, fmaf(v.z, v.z, v.w * v.w)));
#pragma unroll
        for (int off = 16; off >= 1; off >>= 1) s += __shfl_xor(s, off);
        if ((t & 31) == 0) y2[row] = s;
    }
}

// ---- MFMA GEMM (f16, K=128) + top-2 argmin epilogue + streaming output zero ---
// 1-D grid 8192, XCD-swizzled: each XCD gets a contiguous 1024-block chunk
// (16 B-panels + 64 A-panels = 2.5 MB, fits the 4 MB per-XCD L2).
// Zero stores issued right after MFMA so the epilogue reduce hides the drain.
__global__ __launch_bounds__(256) void gemm_mfma(
    const unsigned short* __restrict__ Aext,  // [B][N][128] f16 bits
    const unsigned short* __restrict__ Bext,
    const float* __restrict__ y2g,
    float* __restrict__ pv1, float* __restrict__ pv2, unsigned int* __restrict__ pidx,
    float* __restrict__ outZero)
{
    __shared__ __align__(16) short As[128 * 64];
    __shared__ __align__(16) short Bs[128 * 64];
    __shared__ float rv1[2][128];
    __shared__ float rv2[2][128];
    __shared__ unsigned int ri[2][128];

    const unsigned flat = blockIdx.x;                      // 0..8191
    const unsigned wg   = (flat & 7u) * 1024u + (flat >> 3);  // bijective XCD chunking
    const int bm  = wg & 63;
    const int bnc = (int)((wg >> 6) & 63);
    const int b   = (int)(wg >> 12);

    const int tid  = threadIdx.x;
    const int lane = tid & 63;
    const int wid  = tid >> 6;
    const int wr   = wid >> 1, wc = wid & 1;
    const int l15  = lane & 15, l4 = lane >> 4;
    const int row0 = bm * 128, col0 = bnc * 128;

    const unsigned short* Abase = Aext + ((size_t)b * NPTS + row0) * 128;
    const unsigned short* Bbase = Bext + ((size_t)b * NPTS + col0) * 128;

    f32x4 acc[4][4];
#pragma unroll
    for (int i = 0; i < 4; ++i)
#pragma unroll
        for (int j = 0; j < 4; ++j) acc[i][j] = (f32x4)0.0f;

#pragma unroll
    for (int kk = 0; kk < 2; ++kk) {          // K halves: cols [0,64) and [64,128)
        __syncthreads();
        {
            const int ko = kk * 64;
#pragma unroll
            for (int it = 0; it < 4; ++it) {
                int flat2 = it * 256 + tid;   // 16B-chunk id 0..1023 (128 rows x 8 chunks)
                int r = flat2 >> 3, kc = flat2 & 7;
                int kcs = kc ^ (r & 7);       // inverse-swizzled source chunk
                const unsigned short* ga = Abase + (size_t)r * 128 + ko + kcs * 8;
                const unsigned short* gb = Bbase + (size_t)r * 128 + ko + kcs * 8;
                __builtin_amdgcn_global_load_lds((as1_uint*)ga, (as3_uint*)&As[flat2 * 8], 16, 0, 0);
                __builtin_amdgcn_global_load_lds((as1_uint*)gb, (as3_uint*)&Bs[flat2 * 8], 16, 0, 0);
            }
        }
        __syncthreads();
#pragma unroll
        for (int ks = 0; ks < 2; ++ks) {
            half8v a[4], bf[4];
#pragma unroll
            for (int i = 0; i < 4; ++i) {
                int ra = wr * 64 + i * 16 + l15;
                int ch = ks * 4 + l4;
                a[i] = *reinterpret_cast<const half8v*>(&As[ra * 64 + ((ch ^ (ra & 7)) << 3)]);
            }
#pragma unroll
            for (int j = 0; j < 4; ++j) {
                int rb = wc * 64 + j * 16 + l15;
                int ch = ks * 4 + l4;
                bf[j] = *reinterpret_cast<const half8v*>(&Bs[rb * 64 + ((ch ^ (rb & 7)) << 3)]);
            }
#pragma unroll
            for (int i = 0; i < 4; ++i)
#pragma unroll
                for (int j = 0; j < 4; ++j)
                    acc[i][j] = __builtin_amdgcn_mfma_f32_16x16x32_f16(a[i], bf[j], acc[i][j], 0, 0, 0);
        }
    }

    // hoist y2 loads BEFORE the zero stores (so their vmcnt wait doesn't include them)
    const float* y2b = y2g + b * NPTS;
    float yv[4];
#pragma unroll
    for (int j = 0; j < 4; ++j) yv[j] = y2b[col0 + wc * 64 + j * 16 + l15];

    // streaming zero of this block's 64 KB output slice — issued early so the
    // epilogue's shuffle/LDS reduce hides part of the store drain
    {
        f32x4* o4 = reinterpret_cast<f32x4*>(outZero) + (size_t)wg * 4096;
        const f32x4 z = (f32x4)0.0f;
#pragma unroll
        for (int it = 0; it < 16; ++it)
            __builtin_nontemporal_store(z, &o4[it * 256 + tid]);
    }

#pragma unroll
    for (int i = 0; i < 4; ++i) {
#pragma unroll
        for (int q = 0; q < 4; ++q) {
            float v1 = INFINITY, v2 = INFINITY;
            unsigned int mi = 0u;
#pragma unroll
            for (int j = 0; j < 4; ++j) {
                const float v = fmaf(-2.0f, acc[i][j][q], yv[j]);
                const unsigned int m = (unsigned)(col0 + wc * 64 + j * 16 + l15);
                if (v < v1) { v2 = v1; v1 = v; mi = m; }
                else        { v2 = fminf(v2, v); }
            }
#pragma unroll
            for (int off = 1; off < 16; off <<= 1) {
                float o1 = __shfl_xor(v1, off);
                float o2 = __shfl_xor(v2, off);
                unsigned int oi = __shfl_xor(mi, off);
                if (o1 < v1 || (o1 == v1 && oi < mi)) { v2 = fminf(v1, o2); v1 = o1; mi = oi; }
                else                                  { v2 = fminf(v2, fminf(o1, o2)); }
            }
            if (l15 == 0) {
                const int rl = wr * 64 + i * 16 + l4 * 4 + q;
                rv1[wc][rl] = v1; rv2[wc][rl] = v2; ri[wc][rl] = mi;
            }
        }
    }
    __syncthreads();
    if (tid < 128) {
        float a1 = rv1[0][tid], a2 = rv2[0][tid];
        unsigned int ai = ri[0][tid];
        const float o1 = rv1[1][tid], o2 = rv2[1][tid];
        const unsigned int oi = ri[1][tid];
        if (o1 < a1 || (o1 == a1 && oi < ai)) { a2 = fminf(a1, o2); a1 = o1; ai = oi; }
        else                                  { a2 = fminf(a2, fminf(o1, o2)); }
        const size_t gr = (size_t)b * NPTS + row0 + tid;
        pv1[(size_t)bnc * NROWS + gr] = a1;
        pv2[(size_t)bnc * NROWS + gr] = a2;
        pidx[(size_t)bnc * NROWS + gr] = ai;
    }
}

// ---- merge partials; unflagged rows write output directly; flag near-ties -----
__global__ void resolve_kernel(const float* __restrict__ pv1, const float* __restrict__ pv2,
                               const unsigned int* __restrict__ pidx,
                               float* __restrict__ bestval, float* __restrict__ out,
                               unsigned int* __restrict__ flagList, unsigned int* __restrict__ flagCount)
{
    const int gr = blockIdx.x * 256 + threadIdx.x;
    float a1 = INFINITY, a2 = INFINITY;
    unsigned int ai = 0u;
    for (int cs = 0; cs < NCOLT; ++cs) {
        const float o1 = pv1[(size_t)cs * NROWS + gr];
        const float o2 = pv2[(size_t)cs * NROWS + gr];
        const unsigned int oi = pidx[(size_t)cs * NROWS + gr];
        if (o1 < a1 || (o1 == a1 && oi < ai)) { a2 = fminf(a1, o2); a1 = o1; ai = oi; }
        else                                  { a2 = fminf(a2, fminf(o1, o2)); }
    }
    bestval[gr] = a1;
    if (a2 - a1 < EPSGAP) {
        unsigned int pos = atomicAdd(flagCount, 1u);
        flagList[pos] = (unsigned int)gr;
    } else {
        // final for this row: write one-hot 1.0 and idx tail (zeros laid by gemm)
        out[(size_t)gr * NPTS + ai] = 1.0f;
        out[(size_t)BATCH * NPTS * NPTS + gr] = (float)ai;
    }
}

// ---- candidate-window fp64 recheck: one WAVE per flagged row; writes output ---
__global__ __launch_bounds__(256) void recheck_kernel(
    const float* __restrict__ f0, const float* __restrict__ f1,
    const float* __restrict__ pv1, const float* __restrict__ pv2,
    const unsigned int* __restrict__ pidx, const float* __restrict__ bestval,
    const unsigned int* __restrict__ flagList, const unsigned int* __restrict__ flagCount,
    float* __restrict__ out)
{
    __shared__ float xrow[4][DDIM];
    __shared__ unsigned int cand[4][WCAP];
    __shared__ int ncand[4];

    const int tid  = threadIdx.x;
    const int w    = tid >> 6;
    const int lane = tid & 63;
    const unsigned int nflag = *flagCount;
    const unsigned int slot0 = blockIdx.x * 4 + w;
    const unsigned int nslots = gridDim.x * 4;

    for (unsigned int li = slot0; li < nflag; li += nslots) {
        const int gr = (int)flagList[li];
        const int b = gr >> 13, n = gr & (NPTS - 1);
        const float W = bestval[gr] + EPSGAP;

        if (lane == 0) ncand[w] = 0;
        const float* xp = f0 + ((size_t)b * NPTS + n) * DDIM;
        xrow[w][lane]      = xp[lane];
        xrow[w][lane + 64] = xp[lane + 64];

        // screen: lane == tile index
        {
            const size_t base = (size_t)lane * NROWS + gr;
            const float t1 = pv1[base];
            if (t1 <= W) {
                if (pv2[base] <= W) {
                    int p = atomicAdd(&ncand[w], 128);
                    if (p + 128 <= WCAP)
                        for (int c = 0; c < 128; ++c) cand[w][p + c] = (unsigned)(lane * 128 + c);
                } else {
                    int p = atomicAdd(&ncand[w], 1);
                    if (p < WCAP) cand[w][p] = pidx[base];
                }
            }
        }
        asm volatile("s_waitcnt lgkmcnt(0)" ::: "memory");  // wave-local LDS drain

        const int nc = ncand[w];
        double bv = 1e300;
        unsigned int bi = 0xFFFFFFFFu;
        const float4* xpv = reinterpret_cast<const float4*>(xrow[w]);
        if (nc <= WCAP) {
            for (int c = lane; c < nc; c += 64) {
                const unsigned int m = cand[w][c];
                const float4* ypv = reinterpret_cast<const float4*>(f1 + ((size_t)b * NPTS + m) * DDIM);
                double s0 = 0.0, s1 = 0.0, s2 = 0.0, s3 = 0.0;
#pragma unroll 8
                for (int k4 = 0; k4 < DDIM / 4; ++k4) {
                    const float4 y = ypv[k4];
                    const float4 x = xpv[k4];
                    s0 = fma((double)y.x, (double)y.x - 2.0 * (double)x.x, s0);
                    s1 = fma((double)y.y, (double)y.y - 2.0 * (double)x.y, s1);
                    s2 = fma((double)y.z, (double)y.z - 2.0 * (double)x.z, s2);
                    s3 = fma((double)y.w, (double)y.w - 2.0 * (double)x.w, s3);
                }
                const double v = (s0 + s1) + (s2 + s3);
                if (v < bv || (v == bv && m < bi)) { bv = v; bi = m; }
            }
        } else {
            for (int m = lane; m < NPTS; m += 64) {
                const float4* ypv = reinterpret_cast<const float4*>(f1 + ((size_t)b * NPTS + m) * DDIM);
                double s0 = 0.0, s1 = 0.0, s2 = 0.0, s3 = 0.0;
#pragma unroll 4
                for (int k4 = 0; k4 < DDIM / 4; ++k4) {
                    const float4 y = ypv[k4];
                    const float4 x = xpv[k4];
                    s0 = fma((double)y.x, (double)y.x - 2.0 * (double)x.x, s0);
                    s1 = fma((double)y.y, (double)y.y - 2.0 * (double)x.y, s1);
                    s2 = fma((double)y.z, (double)y.z - 2.0 * (double)x.z, s2);
                    s3 = fma((double)y.w, (double)y.w - 2.0 * (double)x.w, s3);
                }
                const double v = (s0 + s1) + (s2 + s3);
                if (v < bv || (v == bv && (unsigned)m < bi)) { bv = v; bi = (unsigned)m; }
            }
        }
        // wave argmin reduce (exact doubles; first-occurrence tie-break)
#pragma unroll
        for (int off = 1; off < 64; off <<= 1) {
            const double ov = __shfl_xor(bv, off);
            const unsigned int oi = __shfl_xor(bi, off);
            if (ov < bv || (ov == bv && oi < bi)) { bv = ov; bi = oi; }
        }
        if (lane == 0) {
            out[(size_t)gr * NPTS + bi] = 1.0f;
            out[(size_t)BATCH * NPTS * NPTS + gr] = (float)bi;
        }
        asm volatile("s_waitcnt lgkmcnt(0)" ::: "memory");  // before LDS reuse next iter
    }
}

extern "C" void kernel_launch(void* const* d_in, const int* in_sizes, int n_in,
                              void* d_out, int out_size, void* d_ws, size_t ws_size,
                              hipStream_t stream)
{
    const float* f0 = (const float*)d_in[0];
    const float* f1 = (const float*)d_in[1];
    float* out = (float*)d_out;

    // ws layout (bytes): Aext 4.19M | Bext 4.19M | y2 64K | pv1 4.19M | pv2 4.19M
    //                    | pidx 4.19M | bestval 64K | flagList 64K | flagCount 4
    char* wsb = (char*)d_ws;
    unsigned short* Aext = (unsigned short*)wsb;                  wsb += (size_t)BATCH * NPTS * 128 * 2;
    unsigned short* Bext = (unsigned short*)wsb;                  wsb += (size_t)BATCH * NPTS * 128 * 2;
    float* y2            = (float*)wsb;                           wsb += (size_t)NROWS * 4;
    float* pv1           = (float*)wsb;                           wsb += (size_t)NCOLT * NROWS * 4;
    float* pv2           = (float*)wsb;                           wsb += (size_t)NCOLT * NROWS * 4;
    unsigned int* pidx   = (unsigned int*)wsb;                    wsb += (size_t)NCOLT * NROWS * 4;
    float* bestval       = (float*)wsb;                           wsb += (size_t)NROWS * 4;
    unsigned int* flagList = (unsigned int*)wsb;                  wsb += (size_t)NROWS * 4;
    unsigned int* flagCount = (unsigned int*)wsb;

    split_kernel<<<2 * (BATCH * NPTS * 32) / 256, 256, 0, stream>>>(f0, f1, Aext, Bext, y2, flagCount);
    gemm_mfma<<<NPTS / 128 * NPTS / 128 * BATCH, 256, 0, stream>>>(Aext, Bext, y2, pv1, pv2, pidx, out);
    resolve_kernel<<<NROWS / 256, 256, 0, stream>>>(pv1, pv2, pidx, bestval, out, flagList, flagCount);
    recheck_kernel<<<512, 256, 0, stream>>>(f0, f1, pv1, pv2, pidx, bestval, flagList, flagCount, out);
}